// Round 1
// baseline (1559.395 us; speedup 1.0000x reference)
//
#include <hip/hip_runtime.h>

// DISCO S2 convolution, equiangular 360x720 -> 180x360, K=3, B*C=128.
// out[bc, kt, p] = sum_{e in segment kt} val[e]*qw[lat[e]] * x[bc, lat[e], (lon[e]-2p-2) mod 720]
// psi_seg is globally sorted ascending (np.nonzero lexicographic per ik-chunk).

#define NLAT_IN  360
#define NLON_IN  720
#define NLAT_OUT 180
#define NLON_OUT 360
#define KSIZE    3
#define NSEG     (KSIZE * NLAT_OUT)    // 540
#define CHW      (NLAT_IN * NLON_IN)   // 259200
#define BCTOT    128                   // B*C
#define GBC      8                     // bc channels per block

// Build CSR row pointer over the sorted psi_seg array.
__global__ void segptr_kernel(const int* __restrict__ seg, int nnz, int* __restrict__ ptr) {
    int s = blockIdx.x * blockDim.x + threadIdx.x;
    if (s > NSEG) return;
    if (s == NSEG) { ptr[NSEG] = nnz; return; }
    int lo = 0, hi = nnz;
    while (lo < hi) {
        int m = (lo + hi) >> 1;
        if (seg[m] < s) lo = m + 1; else hi = m;
    }
    ptr[s] = lo;
}

__global__ __launch_bounds__(384) void disco_kernel(
    const float* __restrict__ x,
    const float* __restrict__ qw,
    const int*   __restrict__ lat,
    const int*   __restrict__ lon,
    const float* __restrict__ val,
    const int*   __restrict__ ptr,
    float*       __restrict__ out)
{
    const int p = threadIdx.x;
    if (p >= NLON_OUT) return;                 // 24 pad lanes idle, no barriers used
    const int kt  = blockIdx.x;                // 0..539  (k*180 + t)
    const int bc0 = blockIdx.y * GBC;          // 0..120

    const int e0 = ptr[kt];
    const int e1 = ptr[kt + 1];

    float acc[GBC];
#pragma unroll
    for (int g = 0; g < GBC; ++g) acc[g] = 0.0f;

    const int pw = 2 * p + 2;                  // (p+1)*scale, scale=2
    const float* xb = x + (size_t)bc0 * CHW;

    for (int e = e0; e < e1; ++e) {
        const int   h  = lat[e];
        const int   w  = lon[e];
        const float cf = val[e] * qw[h];
        int col = w - pw;                      // in [-720, 717]
        if (col < 0) col += NLON_IN;           // -> [0, 719]
        const float* src = xb + h * NLON_IN + col;
#pragma unroll
        for (int g = 0; g < GBC; ++g)
            acc[g] = fmaf(cf, src[(size_t)g * CHW], acc[g]);
    }

    // out layout: [B, C, K, T, P] -> ((bc*NSEG) + kt)*NLON_OUT + p
    const size_t ob = ((size_t)bc0 * NSEG + kt) * NLON_OUT + p;
#pragma unroll
    for (int g = 0; g < GBC; ++g)
        out[ob + (size_t)g * NSEG * NLON_OUT] = acc[g];
}

extern "C" void kernel_launch(void* const* d_in, const int* in_sizes, int n_in,
                              void* d_out, int out_size, void* d_ws, size_t ws_size,
                              hipStream_t stream)
{
    const float* x   = (const float*)d_in[0];   // [2,64,360,720] f32
    const float* qw  = (const float*)d_in[1];   // [360,1] f32
    const int*   seg = (const int*)  d_in[2];   // [nnz] i32, sorted ascending
    const int*   lat = (const int*)  d_in[3];   // [nnz] i32
    const int*   lon = (const int*)  d_in[4];   // [nnz] i32
    const float* val = (const float*)d_in[5];   // [nnz] f32
    const int    nnz = in_sizes[2];

    int* ptr = (int*)d_ws;                      // 541 ints = 2164 B of scratch

    segptr_kernel<<<(NSEG + 1 + 255) / 256, 256, 0, stream>>>(seg, nnz, ptr);

    dim3 grid(NSEG, BCTOT / GBC);
    disco_kernel<<<grid, 384, 0, stream>>>(x, qw, lat, lon, val, ptr,
                                           (float*)d_out);
}

// Round 2
// 1202.327 us; speedup vs baseline: 1.2970x; 1.2970x over previous
//
#include <hip/hip_runtime.h>

// DISCO S2 conv, equiangular 360x720 -> 180x360, K=3, B*C=128.
// out[bc, k*180+t, p] = sum_{e in seg} vq[e] * x[bc, lat[e], (lon[e]-2p-2) mod 720]
// with vq[e] = val[e]*qw[lat[e]].
//
// Round-2 structure: per block = (bc-group of 4, t). The support cap of output
// latitude t spans <= 6 input rows (|h - 2.0056 t| < 2.99). Stage those rows
// for 4 channels in LDS, parity-deinterleaved: lds[row][w&1][w>>1][g]. Then
// each entry is: scalar (row,parity,s0,cf) + per-lane j=(s0-p) mod 360 and one
// ds_read_b128 (4 channels contiguous) + 4 FMA. All 3 ik segments of t share
// the same rows -> amortize staging 3x. Pole blocks (heaviest) dispatch first.

#define NLAT_IN  360
#define NLON_IN  720
#define NLAT_OUT 180
#define NLON_OUT 360
#define KSIZE    3
#define NSEG     (KSIZE * NLAT_OUT)    // 540
#define CHW      (NLAT_IN * NLON_IN)   // 259200
#define BCTOT    128
#define G        4                     // channels per block
#define NBCG     (BCTOT / G)           // 32
#define MAXR     5                     // rows staged per chunk (5*2*360*4*4B = 57.6 KB)
#define NTHREADS 384

// CSR row pointer over sorted psi_seg.
__global__ void segptr_kernel(const int* __restrict__ seg, int nnz, int* __restrict__ ptr) {
    int s = blockIdx.x * blockDim.x + threadIdx.x;
    if (s > NSEG) return;
    if (s == NSEG) { ptr[NSEG] = nnz; return; }
    int lo = 0, hi = nnz;
    while (lo < hi) {
        int m = (lo + hi) >> 1;
        if (seg[m] < s) lo = m + 1; else hi = m;
    }
    ptr[s] = lo;
}

// Pre-fold quadrature weight into val: vq[e] = val[e]*qw[lat[e]].
__global__ void vq_kernel(const int* __restrict__ lat, const float* __restrict__ val,
                          const float* __restrict__ qw, int nnz, float* __restrict__ vq) {
    int e = blockIdx.x * blockDim.x + threadIdx.x;
    if (e < nnz) vq[e] = val[e] * qw[lat[e]];
}

__global__ __launch_bounds__(NTHREADS) void disco_kernel(
    const float* __restrict__ x,
    const int*   __restrict__ lat,
    const int*   __restrict__ lon,
    const float* __restrict__ vq,    // val (pre-scaled if qwp==nullptr)
    const float* __restrict__ qwp,   // nullptr when vq is pre-scaled
    const int*   __restrict__ ptr,
    float*       __restrict__ out)
{
    __shared__ float lds[MAXR][2][NLON_OUT][G];   // 57,600 B -> 2 blocks/CU

    const int tid = threadIdx.x;
    const int bc0 = blockIdx.x * G;               // 0..124
    const int ty  = blockIdx.y;                   // 0..179
    // heavy pole segments first: t = 0,179,1,178,...
    const int t = (ty & 1) ? (NLAT_OUT - 1 - (ty >> 1)) : (ty >> 1);

    int e0[KSIZE], e1[KSIZE];
    int hmin = 0x7fffffff, hmax = -1;
#pragma unroll
    for (int k = 0; k < KSIZE; ++k) {
        const int s = k * NLAT_OUT + t;
        e0[k] = ptr[s];
        e1[k] = ptr[s + 1];
        if (e1[k] > e0[k]) {                       // entries sorted by (h,w) in-segment
            hmin = min(hmin, lat[e0[k]]);
            hmax = max(hmax, lat[e1[k] - 1]);
        }
    }

    float acc[KSIZE][G];
#pragma unroll
    for (int k = 0; k < KSIZE; ++k)
#pragma unroll
        for (int g = 0; g < G; ++g) acc[k][g] = 0.0f;

    const int p  = tid;
    const int pp = (p < NLON_OUT) ? p : 0;        // pad lanes compute garbage, don't store

    if (hmax >= hmin) {
        for (int r0 = hmin; r0 <= hmax; r0 += MAXR) {
            const int rn = min(MAXR, hmax - r0 + 1);
            __syncthreads();                       // previous chunk's readers done
            // ---- stage rows r0..r0+rn-1 for G channels, parity-deinterleaved ----
#pragma unroll
            for (int g = 0; g < G; ++g) {
                const float* xr = x + (size_t)(bc0 + g) * CHW + (size_t)r0 * NLON_IN;
                for (int r = 0; r < rn; ++r)
                    for (int w = tid; w < NLON_IN; w += NTHREADS)
                        lds[r][w & 1][w >> 1][g] = xr[r * NLON_IN + w];
            }
            __syncthreads();
            // ---- accumulate all entries whose row lies in this chunk ----
#pragma unroll
            for (int k = 0; k < KSIZE; ++k) {
                for (int e = e0[k]; e < e1[k]; ++e) {
                    const int h = lat[e];
                    if (h < r0 || h >= r0 + rn) continue;   // wave-uniform skip
                    const int w = lon[e];
                    float cf = vq[e];
                    if (qwp) cf *= qwp[h];                  // ws-too-small fallback
                    // col = (w-2-2p) mod 720; parity = w&1; j = (s0 - p) mod 360
                    const int s0 = ((w >> 1) + NLON_OUT - 1) % NLON_OUT;
                    int j = s0 - pp;
                    if (j < 0) j += NLON_OUT;
                    const float4 xv = *(const float4*)&lds[h - r0][w & 1][j][0];
                    acc[k][0] = fmaf(cf, xv.x, acc[k][0]);
                    acc[k][1] = fmaf(cf, xv.y, acc[k][1]);
                    acc[k][2] = fmaf(cf, xv.z, acc[k][2]);
                    acc[k][3] = fmaf(cf, xv.w, acc[k][3]);
                }
            }
        }
    }

    if (p < NLON_OUT) {
        // out flat: ((bc*NSEG) + k*NLAT_OUT + t)*NLON_OUT + p
#pragma unroll
        for (int k = 0; k < KSIZE; ++k)
#pragma unroll
            for (int g = 0; g < G; ++g)
                out[((size_t)(bc0 + g) * NSEG + k * NLAT_OUT + t) * NLON_OUT + p] = acc[k][g];
    }
}

extern "C" void kernel_launch(void* const* d_in, const int* in_sizes, int n_in,
                              void* d_out, int out_size, void* d_ws, size_t ws_size,
                              hipStream_t stream)
{
    const float* x   = (const float*)d_in[0];   // [2,64,360,720] f32
    const float* qw  = (const float*)d_in[1];   // [360,1] f32
    const int*   seg = (const int*)  d_in[2];   // [nnz] i32 sorted asc
    const int*   lat = (const int*)  d_in[3];
    const int*   lon = (const int*)  d_in[4];
    const float* val = (const float*)d_in[5];
    const int    nnz = in_sizes[2];

    int*   ptr = (int*)d_ws;                    // 541 ints
    float* vq  = (float*)((char*)d_ws + 2176);  // nnz floats (8B-aligned block)
    const bool have_vq = ws_size >= (size_t)2176 + (size_t)nnz * 4;

    segptr_kernel<<<(NSEG + 1 + 255) / 256, 256, 0, stream>>>(seg, nnz, ptr);

    const float* vq_arg = val;
    const float* qw_arg = qw;
    if (have_vq) {
        vq_kernel<<<(nnz + 255) / 256, 256, 0, stream>>>(lat, val, qw, nnz, vq);
        vq_arg = vq;
        qw_arg = nullptr;
    }

    dim3 grid(NBCG, NLAT_OUT);                  // bc-groups fastest -> pole blocks first
    disco_kernel<<<grid, NTHREADS, 0, stream>>>(x, lat, lon, vq_arg, qw_arg, ptr,
                                                (float*)d_out);
}

// Round 3
// 217.686 us; speedup vs baseline: 7.1635x; 5.5232x over previous
//
#include <hip/hip_runtime.h>

// DISCO S2 conv, equiangular 360x720 -> 180x360, K=3, B*C=128.
// out[bc, k*180+t, p] = sum_{e in seg(k,t)} val[e]*qw[lat[e]] * x[bc, lat[e], (lon[e]-2p-2) mod 720]
//
// Round-3: branch-free LDS-resident inner loop.
//  - psi entries are sorted by (h,w) within each segment (np.nonzero order).
//  - prep builds ptr[seg] (CSR) and ptrh[seg][0..8] (per-row sub-pointers,
//    row span per segment <= 6 rows since |h - 2.0056 t| < 2.99).
//  - block (bc-group of 4, t): slide a 3-row x-window staged in LDS as
//    float4 ldsx[rowpar][j] (parity-deinterleaved, 4 channels per float4);
//    per window/segment, bulk-load the entry range, pack {s0|rp<<9, cf} in
//    LDS meta; hot loop: decode -> j=(s0-p)%360 -> ds_read_b128 -> 4 FMA.
//  - 40.7 KB LDS -> 4 blocks/CU (24 waves/CU).

#define NLAT_IN  360
#define NLON_IN  720
#define NLAT_OUT 180
#define NLON_OUT 360
#define KSIZE    3
#define NSEG     (KSIZE * NLAT_OUT)    // 540
#define CHW      (NLAT_IN * NLON_IN)   // 259200
#define BCTOT    128
#define G        4                     // channels per block
#define NBCG     (BCTOT / G)           // 32
#define MAXR     3                     // staged rows per window
#define MCH      768                   // meta chunk (entries)
#define NTHREADS 384

// CSR row pointer over sorted psi_seg.
__global__ void segptr_kernel(const int* __restrict__ seg, int nnz, int* __restrict__ ptr) {
    int s = blockIdx.x * blockDim.x + threadIdx.x;
    if (s > NSEG) return;
    if (s == NSEG) { ptr[NSEG] = nnz; return; }
    int lo = 0, hi = nnz;
    while (lo < hi) {
        int m = (lo + hi) >> 1;
        if (seg[m] < s) lo = m + 1; else hi = m;
    }
    ptr[s] = lo;
}

// Per-segment per-row pointers: ptrh[s*9+j] = first e in [e0,e1) with lat[e] >= lat[e0]+j.
__global__ void ptrh_kernel(const int* __restrict__ lat, const int* __restrict__ ptr,
                            int* __restrict__ ptrh) {
    int idx = blockIdx.x * blockDim.x + threadIdx.x;   // s*9 + j
    if (idx >= NSEG * 9) return;
    int s = idx / 9, j = idx - s * 9;
    int e0 = ptr[s], e1 = ptr[s + 1];
    if (e0 >= e1) { ptrh[idx] = e0; return; }
    int target = lat[e0] + j;
    int lo = e0, hi = e1;
    while (lo < hi) {
        int m = (lo + hi) >> 1;
        if (lat[m] < target) lo = m + 1; else hi = m;
    }
    ptrh[idx] = lo;
}

__global__ __launch_bounds__(NTHREADS, 6) void disco_kernel(
    const float* __restrict__ x,
    const float* __restrict__ qw,
    const int*   __restrict__ lat,
    const int*   __restrict__ lon,
    const float* __restrict__ val,
    const int*   __restrict__ ptr,
    const int*   __restrict__ ptrh,
    float*       __restrict__ out)
{
    __shared__ float4 ldsx[MAXR * 2][NLON_OUT];   // [rowpar][j], 34,560 B
    __shared__ uint2  ldsm[MCH];                  // packed meta, 6,144 B

    const int tid = threadIdx.x;
    const int bc0 = blockIdx.x * G;
    const int ty  = blockIdx.y;
    const int t   = (ty & 1) ? (NLAT_OUT - 1 - (ty >> 1)) : (ty >> 1);  // poles first

    int e0[KSIZE], e1[KSIZE], hb[KSIZE];
    int hmin = 0x7fffffff, hmax = -1;
#pragma unroll
    for (int k = 0; k < KSIZE; ++k) {
        const int s = k * NLAT_OUT + t;
        e0[k] = ptr[s]; e1[k] = ptr[s + 1];
        if (e1[k] > e0[k]) {
            hb[k] = lat[e0[k]];
            hmin = min(hmin, hb[k]);
            hmax = max(hmax, lat[e1[k] - 1]);
        } else hb[k] = 0x7fffffff;
    }

    float acc[KSIZE][G];
#pragma unroll
    for (int k = 0; k < KSIZE; ++k)
#pragma unroll
        for (int g = 0; g < G; ++g) acc[k][g] = 0.0f;

    const int p = (tid < NLON_OUT) ? tid : 0;     // pad lanes mirror lane 0

    for (int r0 = hmin; r0 <= hmax; r0 += MAXR) {
        const int rn = min(MAXR, hmax - r0 + 1);
        __syncthreads();                           // prior window readers done
        // ---- stage rows r0..r0+rn-1 (G channels) parity-deinterleaved ----
#pragma unroll
        for (int g = 0; g < G; ++g) {
            const float* xr = x + (size_t)(bc0 + g) * CHW + (size_t)r0 * NLON_IN;
            for (int r = 0; r < rn; ++r) {
                if (tid < NLON_OUT) {
                    const float2 v = *(const float2*)&xr[r * NLON_IN + 2 * tid];
                    ((float*)&ldsx[r * 2 + 0][tid])[g] = v.x;
                    ((float*)&ldsx[r * 2 + 1][tid])[g] = v.y;
                }
            }
        }
        __syncthreads();
        // ---- segments ----
        for (int k = 0; k < KSIZE; ++k) {
            if (e0[k] >= e1[k]) continue;          // uniform
            int jlo = min(max(r0 - hb[k], 0), 8);
            int jhi = min(max(r0 + rn - hb[k], 0), 8);
            const int* ph = ptrh + (size_t)(k * NLAT_OUT + t) * 9;
            const int cs = ph[jlo], ce = ph[jhi];
            for (int mb = cs; mb < ce; mb += MCH) {
                const int cnt = min(MCH, ce - mb);
                __syncthreads();                   // prior chunk readers done
                for (int i = tid; i < cnt; i += NTHREADS) {
                    const int e = mb + i;
                    const int h = lat[e];
                    const int w = lon[e];
                    const float cf = val[e] * qw[h];
                    const int i0 = w >> 1;
                    const int s0 = (i0 == 0) ? (NLON_OUT - 1) : (i0 - 1);
                    const int rp = (h - r0) * 2 + (w & 1);
                    ldsm[i] = make_uint2((unsigned)(s0 | (rp << 9)), __float_as_uint(cf));
                }
                __syncthreads();
#pragma unroll 4
                for (int m = 0; m < cnt; ++m) {
                    const uint2 me = ldsm[m];      // uniform addr -> broadcast
                    const int   s0 = me.x & 511;
                    const int   rp = me.x >> 9;
                    const float cf = __uint_as_float(me.y);
                    int j = s0 - p; if (j < 0) j += NLON_OUT;
                    const float4 xv = ldsx[rp][j]; // contiguous across lanes
                    acc[k][0] = fmaf(cf, xv.x, acc[k][0]);
                    acc[k][1] = fmaf(cf, xv.y, acc[k][1]);
                    acc[k][2] = fmaf(cf, xv.z, acc[k][2]);
                    acc[k][3] = fmaf(cf, xv.w, acc[k][3]);
                }
            }
        }
    }

    if (tid < NLON_OUT) {
#pragma unroll
        for (int k = 0; k < KSIZE; ++k)
#pragma unroll
            for (int g = 0; g < G; ++g)
                out[((size_t)(bc0 + g) * NSEG + k * NLAT_OUT + t) * NLON_OUT + tid] = acc[k][g];
    }
}

extern "C" void kernel_launch(void* const* d_in, const int* in_sizes, int n_in,
                              void* d_out, int out_size, void* d_ws, size_t ws_size,
                              hipStream_t stream)
{
    const float* x   = (const float*)d_in[0];   // [2,64,360,720] f32
    const float* qw  = (const float*)d_in[1];   // [360,1] f32
    const int*   seg = (const int*)  d_in[2];   // [nnz] i32 sorted asc
    const int*   lat = (const int*)  d_in[3];
    const int*   lon = (const int*)  d_in[4];
    const float* val = (const float*)d_in[5];
    const int    nnz = in_sizes[2];

    int* ptr  = (int*)d_ws;                     // 541 ints (pad to 544)
    int* ptrh = (int*)((char*)d_ws + 2176);     // 540*9 ints = 19,440 B

    segptr_kernel<<<(NSEG + 1 + 255) / 256, 256, 0, stream>>>(seg, nnz, ptr);
    ptrh_kernel<<<(NSEG * 9 + 255) / 256, 256, 0, stream>>>(lat, ptr, ptrh);

    dim3 grid(NBCG, NLAT_OUT);
    disco_kernel<<<grid, NTHREADS, 0, stream>>>(x, qw, lat, lon, val, ptr, ptrh,
                                                (float*)d_out);
}

// Round 4
// 209.773 us; speedup vs baseline: 7.4337x; 1.0377x over previous
//
#include <hip/hip_runtime.h>

// DISCO S2 conv, equiangular 360x720 -> 180x360, K=3, B*C=128.
// out[bc, k*180+t, p] = sum_{e in seg(k,t)} val[e]*qw[lat[e]] * x[bc, lat[e], (lon[e]-2p-2) mod 720]
//
// Round-4:
//  - packed meta qm[e] = {s0 | par<<9, cf=val*qw} in d_ws; inner loop reads it
//    with wave-uniform s_load -> SALU decode; per-lane work = j=(s0-p)%360,
//    one ds_read_b128 of ldsx[2r+par][j] (4 channels), 4 FMA.
//  - full-row collapse: rows where a segment has 720 entries with constant val
//    (poles: theta is w-independent) satisfy out[p] = cf * rowsum(h) for ALL p.
//    Flagged in prep; block computes rowsum by shuffle-reduce over staged LDS
//    and adds uniformly. Removes ~40% of entries AND the pole-block tail.
//  - x staged in sliding 3-row windows, parity-deinterleaved float4[rp][j]
//    (34.6 KB LDS -> 4 blocks/CU).

#define NLAT_IN  360
#define NLON_IN  720
#define NLAT_OUT 180
#define NLON_OUT 360
#define KSIZE    3
#define NSEG     (KSIZE * NLAT_OUT)    // 540
#define CHW      (NLAT_IN * NLON_IN)   // 259200
#define BCTOT    128
#define G        4
#define NBCG     (BCTOT / G)           // 32
#define MAXR     3
#define PH       10                    // per-seg row sub-pointers (span <= 9 rows)
#define NTHREADS 384

// ---------------- prep kernels ----------------

__global__ void segptr_kernel(const int* __restrict__ seg, int nnz, int* __restrict__ ptr) {
    int s = blockIdx.x * blockDim.x + threadIdx.x;
    if (s > NSEG) return;
    if (s == NSEG) { ptr[NSEG] = nnz; return; }
    int lo = 0, hi = nnz;
    while (lo < hi) { int m = (lo + hi) >> 1; if (seg[m] < s) lo = m + 1; else hi = m; }
    ptr[s] = lo;
}

// ptrh[s*PH+j] = first e in [e0,e1) with lat[e] >= lat[e0]+j ; also hbase/hlast.
__global__ void ptrh_kernel(const int* __restrict__ lat, const int* __restrict__ ptr,
                            int* __restrict__ ptrh, int* __restrict__ hbase,
                            int* __restrict__ hlast) {
    int idx = blockIdx.x * blockDim.x + threadIdx.x;   // s*PH + j
    if (idx >= NSEG * PH) return;
    int s = idx / PH, j = idx - s * PH;
    int e0 = ptr[s], e1 = ptr[s + 1];
    if (e0 >= e1) {
        ptrh[idx] = e0;
        if (j == 0) { hbase[s] = 1 << 28; hlast[s] = -(1 << 28); }
        return;
    }
    int hb = lat[e0];
    if (j == 0) { hbase[s] = hb; hlast[s] = lat[e1 - 1]; }
    int target = hb + j;
    int lo = e0, hi = e1;
    while (lo < hi) { int m = (lo + hi) >> 1; if (lat[m] < target) lo = m + 1; else hi = m; }
    ptrh[idx] = lo;
}

// flag full rows: exactly 720 entries (one per w) with (near-)constant val.
__global__ void flag_kernel(const float* __restrict__ val, const int* __restrict__ ptrh,
                            int* __restrict__ flags) {
    int idx = blockIdx.x * blockDim.x + threadIdx.x;   // s*PH + j
    if (idx >= NSEG * PH) return;
    int j = idx % PH;
    int f = 0;
    if (j < PH - 1) {
        int a = ptrh[idx], b = ptrh[idx + 1];
        if (b - a == NLON_IN) {
            float v0 = val[a], v1 = val[a + 240], v2 = val[a + 480];
            float d = fmaxf(fabsf(v0 - v1), fmaxf(fabsf(v0 - v2), fabsf(v1 - v2)));
            f = (d < 1e-5f) ? 1 : 0;
        }
    }
    flags[idx] = f;
}

// qm[e] = { s0 | par<<9 , cf } with s0=((w>>1)-1) mod 360, par=w&1, cf=val*qw[lat].
__global__ void qmeta_kernel(const int* __restrict__ lat, const int* __restrict__ lon,
                             const float* __restrict__ val, const float* __restrict__ qw,
                             int nnz, uint2* __restrict__ qm) {
    int e = blockIdx.x * blockDim.x + threadIdx.x;
    if (e >= nnz) return;
    int w = lon[e];
    int i0 = w >> 1;
    int s0 = i0 ? (i0 - 1) : (NLON_OUT - 1);
    qm[e] = make_uint2((unsigned)(s0 | ((w & 1) << 9)),
                       __float_as_uint(val[e] * qw[lat[e]]));
}

// ---------------- main kernel ----------------

__global__ __launch_bounds__(NTHREADS) void disco_kernel(
    const float* __restrict__ x,
    const uint2* __restrict__ qm,
    const int*   __restrict__ ptr,
    const int*   __restrict__ ptrh,
    const int*   __restrict__ hbase,
    const int*   __restrict__ hlast,
    const int*   __restrict__ flags,
    float*       __restrict__ out)
{
    __shared__ float4 ldsx[MAXR * 2][NLON_OUT];   // 34,560 B
    __shared__ float4 rsum_lds[MAXR];
    __shared__ float4 wred[NTHREADS / 64];

    const int tid  = threadIdx.x;
    const int lane = tid & 63, wid = tid >> 6;
    const int bc0  = blockIdx.x * G;
    const int ty   = blockIdx.y;
    const int t    = (ty & 1) ? (NLAT_OUT - 1 - (ty >> 1)) : (ty >> 1);  // poles first

    int hb[KSIZE];
    int hmin = 1 << 28, hmax = -(1 << 28);
#pragma unroll
    for (int k = 0; k < KSIZE; ++k) {
        const int s = k * NLAT_OUT + t;
        hb[k] = hbase[s];
        if (ptr[s + 1] > ptr[s]) { hmin = min(hmin, hb[k]); hmax = max(hmax, hlast[s]); }
    }

    float acc[KSIZE][G] = {};
    const int p = (tid < NLON_OUT) ? tid : 0;     // pad lanes mirror lane 0

    for (int r0 = hmin; r0 <= hmax; r0 += MAXR) {
        const int rn = min(MAXR, hmax - r0 + 1);
        __syncthreads();                           // prior window readers done
        // ---- stage rows r0..r0+rn-1 (G channels), parity-deinterleaved ----
#pragma unroll
        for (int g = 0; g < G; ++g) {
            const float* xr = x + (size_t)(bc0 + g) * CHW + (size_t)r0 * NLON_IN;
            for (int r = 0; r < rn; ++r) {
                if (tid < NLON_OUT) {
                    const float2 v = *(const float2*)&xr[r * NLON_IN + 2 * tid];
                    ((float*)&ldsx[r * 2 + 0][tid])[g] = v.x;
                    ((float*)&ldsx[r * 2 + 1][tid])[g] = v.y;
                }
            }
        }
        __syncthreads();
        // ---- rowsum reduce for flagged rows in this window ----
        for (int r = 0; r < rn; ++r) {
            const int row = r0 + r;
            int anyf = 0;
#pragma unroll
            for (int k = 0; k < KSIZE; ++k) {
                const int j = row - hb[k];
                if (j >= 0 && j < PH - 1) anyf |= flags[(k * NLAT_OUT + t) * PH + j];
            }
            if (anyf) {                            // block-uniform branch
                float4 v = make_float4(0.f, 0.f, 0.f, 0.f);
                if (tid < NLON_OUT) {
                    const float4 a_ = ldsx[r * 2][tid], b_ = ldsx[r * 2 + 1][tid];
                    v = make_float4(a_.x + b_.x, a_.y + b_.y, a_.z + b_.z, a_.w + b_.w);
                }
#pragma unroll
                for (int off = 32; off >= 1; off >>= 1) {
                    v.x += __shfl_down(v.x, off);
                    v.y += __shfl_down(v.y, off);
                    v.z += __shfl_down(v.z, off);
                    v.w += __shfl_down(v.w, off);
                }
                if (lane == 0) wred[wid] = v;
                __syncthreads();
                if (wid == 0) {
                    float4 u = (lane < NTHREADS / 64) ? wred[lane]
                                                      : make_float4(0.f, 0.f, 0.f, 0.f);
#pragma unroll
                    for (int off = 4; off >= 1; off >>= 1) {
                        u.x += __shfl_down(u.x, off);
                        u.y += __shfl_down(u.y, off);
                        u.z += __shfl_down(u.z, off);
                        u.w += __shfl_down(u.w, off);
                    }
                    if (lane == 0) rsum_lds[r] = u;
                }
                __syncthreads();
            }
        }
        // ---- accumulate ----
#pragma unroll
        for (int k = 0; k < KSIZE; ++k) {
            const int sseg = k * NLAT_OUT + t;
            for (int r = 0; r < rn; ++r) {
                const int j = (r0 + r) - hb[k];
                if (j < 0 || j >= PH - 1) continue;
                const int a = ptrh[sseg * PH + j], b = ptrh[sseg * PH + j + 1];
                if (a >= b) continue;
                if (flags[sseg * PH + j]) {
                    const float  cf = __uint_as_float(qm[a].y);
                    const float4 rs = rsum_lds[r];   // out[p] == cf*rowsum, all p
                    acc[k][0] = fmaf(cf, rs.x, acc[k][0]);
                    acc[k][1] = fmaf(cf, rs.y, acc[k][1]);
                    acc[k][2] = fmaf(cf, rs.z, acc[k][2]);
                    acc[k][3] = fmaf(cf, rs.w, acc[k][3]);
                } else {
#pragma unroll 4
                    for (int e = a; e < b; ++e) {
                        const uint2 me = qm[e];        // uniform -> s_load
                        const int   s0  = me.x & 511;  // SALU
                        const int   par = (me.x >> 9) & 1;
                        const float cf  = __uint_as_float(me.y);
                        int j2 = s0 - p;
                        j2 += (j2 >> 31) & NLON_OUT;
                        const float4 xv = ldsx[r * 2 + par][j2];
                        acc[k][0] = fmaf(cf, xv.x, acc[k][0]);
                        acc[k][1] = fmaf(cf, xv.y, acc[k][1]);
                        acc[k][2] = fmaf(cf, xv.z, acc[k][2]);
                        acc[k][3] = fmaf(cf, xv.w, acc[k][3]);
                    }
                }
            }
        }
    }

    if (tid < NLON_OUT) {
#pragma unroll
        for (int k = 0; k < KSIZE; ++k)
#pragma unroll
            for (int g = 0; g < G; ++g)
                out[((size_t)(bc0 + g) * NSEG + k * NLAT_OUT + t) * NLON_OUT + tid] = acc[k][g];
    }
}

// ---------------- fallback (tiny ws): round-1 direct kernel ----------------

__global__ __launch_bounds__(384) void disco_simple_kernel(
    const float* __restrict__ x, const float* __restrict__ qw,
    const int* __restrict__ lat, const int* __restrict__ lon,
    const float* __restrict__ val, const int* __restrict__ ptr,
    float* __restrict__ out)
{
    const int p = threadIdx.x;
    if (p >= NLON_OUT) return;
    const int kt = blockIdx.x, bc0 = blockIdx.y * 8;
    const int e0 = ptr[kt], e1 = ptr[kt + 1];
    float acc[8];
#pragma unroll
    for (int g = 0; g < 8; ++g) acc[g] = 0.0f;
    const int pw = 2 * p + 2;
    const float* xb = x + (size_t)bc0 * CHW;
    for (int e = e0; e < e1; ++e) {
        const int h = lat[e], w = lon[e];
        const float cf = val[e] * qw[h];
        int col = w - pw; if (col < 0) col += NLON_IN;
        const float* src = xb + h * NLON_IN + col;
#pragma unroll
        for (int g = 0; g < 8; ++g) acc[g] = fmaf(cf, src[(size_t)g * CHW], acc[g]);
    }
    const size_t ob = ((size_t)bc0 * NSEG + kt) * NLON_OUT + p;
#pragma unroll
    for (int g = 0; g < 8; ++g) out[ob + (size_t)g * NSEG * NLON_OUT] = acc[g];
}

// ---------------- launcher ----------------

extern "C" void kernel_launch(void* const* d_in, const int* in_sizes, int n_in,
                              void* d_out, int out_size, void* d_ws, size_t ws_size,
                              hipStream_t stream)
{
    const float* x   = (const float*)d_in[0];   // [2,64,360,720] f32
    const float* qw  = (const float*)d_in[1];   // [360,1] f32
    const int*   seg = (const int*)  d_in[2];   // [nnz] i32 sorted asc
    const int*   lat = (const int*)  d_in[3];
    const int*   lon = (const int*)  d_in[4];
    const float* val = (const float*)d_in[5];
    const int    nnz = in_sizes[2];

    // ws layout
    char* w = (char*)d_ws;
    int*   ptr   = (int*)w;                       size_t off = 544 * 4;          // 2176
    int*   ptrh  = (int*)(w + off);               off += (size_t)NSEG * PH * 4;  // 21600
    int*   hbase = (int*)(w + off);               off += NSEG * 4;
    int*   hlast = (int*)(w + off);               off += NSEG * 4;
    int*   flags = (int*)(w + off);               off += (size_t)NSEG * PH * 4;
    off = (off + 7) & ~(size_t)7;
    uint2* qm    = (uint2*)(w + off);             off += (size_t)nnz * 8;

    segptr_kernel<<<(NSEG + 1 + 255) / 256, 256, 0, stream>>>(seg, nnz, ptr);

    if (ws_size < off) {
        // scratch too small for the fast path: direct kernel (correct, slower)
        dim3 grid(NSEG, BCTOT / 8);
        disco_simple_kernel<<<grid, 384, 0, stream>>>(x, qw, lat, lon, val, ptr,
                                                      (float*)d_out);
        return;
    }

    ptrh_kernel<<<(NSEG * PH + 255) / 256, 256, 0, stream>>>(lat, ptr, ptrh, hbase, hlast);
    flag_kernel<<<(NSEG * PH + 255) / 256, 256, 0, stream>>>(val, ptrh, flags);
    qmeta_kernel<<<(nnz + 255) / 256, 256, 0, stream>>>(lat, lon, val, qw, nnz, qm);

    dim3 grid(NBCG, NLAT_OUT);
    disco_kernel<<<grid, NTHREADS, 0, stream>>>(x, qm, ptr, ptrh, hbase, hlast, flags,
                                                (float*)d_out);
}

// Round 5
// 198.483 us; speedup vs baseline: 7.8566x; 1.0569x over previous
//
#include <hip/hip_runtime.h>

// DISCO S2 conv, equiangular 360x720 -> 180x360, K=3, B*C=128.
// out[bc, k*180+t, p] = sum_{e in seg(k,t)} val[e]*qw[lat[e]] * x[bc, lat[e], (lon[e]-2p-2) mod 720]
//
// Round-5:
//  - grid (bcg, t, k): one segment per block (k-split -> heavy pole-t work /3,
//    disjoint outputs, no atomics; 17280 blocks for backfill).
//  - SoA meta mx[e] = s0 | (rp*5760)<<9 (LDS byte-offset pre-baked; rp from
//    (h-hbase)%MAXR so it matches the window phase), mc[e] = val*qw.
//    Hot loop: aligned uint4/float4 quad loads, 8 entries/iter; per entry:
//    ~6 int VALU + 1 ds_read_b128 + 4 FMA. No per-entry dependent loads.
//  - conflict-free LDS staging: gather 4 channels -> contiguous b128 writes.
//  - full-row collapse (constant-val rows, poles) via block shuffle-reduce.

#define NLAT_IN  360
#define NLON_IN  720
#define NLAT_OUT 180
#define NLON_OUT 360
#define KSIZE    3
#define NSEG     (KSIZE * NLAT_OUT)    // 540
#define CHW      (NLAT_IN * NLON_IN)   // 259200
#define BCTOT    128
#define G        4
#define NBCG     (BCTOT / G)           // 32
#define MAXR     3
#define PH       10                    // per-seg row sub-pointers
#define NTHREADS 384
#define ROWB     (NLON_OUT * 16)       // 5760 bytes per ldsx row

// ---------------- prep kernels ----------------

__global__ void segptr_kernel(const int* __restrict__ seg, int nnz, int* __restrict__ ptr) {
    int s = blockIdx.x * blockDim.x + threadIdx.x;
    if (s > NSEG) return;
    if (s == NSEG) { ptr[NSEG] = nnz; return; }
    int lo = 0, hi = nnz;
    while (lo < hi) { int m = (lo + hi) >> 1; if (seg[m] < s) lo = m + 1; else hi = m; }
    ptr[s] = lo;
}

__global__ void ptrh_kernel(const int* __restrict__ lat, const int* __restrict__ ptr,
                            int* __restrict__ ptrh, int* __restrict__ hbase,
                            int* __restrict__ hlast) {
    int idx = blockIdx.x * blockDim.x + threadIdx.x;   // s*PH + j
    if (idx >= NSEG * PH) return;
    int s = idx / PH, j = idx - s * PH;
    int e0 = ptr[s], e1 = ptr[s + 1];
    if (e0 >= e1) {
        ptrh[idx] = e0;
        if (j == 0) { hbase[s] = 1 << 28; hlast[s] = -(1 << 28); }
        return;
    }
    int hb = lat[e0];
    if (j == 0) { hbase[s] = hb; hlast[s] = lat[e1 - 1]; }
    int target = hb + j;
    int lo = e0, hi = e1;
    while (lo < hi) { int m = (lo + hi) >> 1; if (lat[m] < target) lo = m + 1; else hi = m; }
    ptrh[idx] = lo;
}

// flag rows with exactly 720 entries and constant val (theta w-independent at poles)
__global__ void flag_kernel(const float* __restrict__ val, const int* __restrict__ ptrh,
                            int* __restrict__ flags) {
    int idx = blockIdx.x * blockDim.x + threadIdx.x;   // s*PH + j
    if (idx >= NSEG * PH) return;
    int j = idx % PH;
    int f = 0;
    if (j < PH - 1) {
        int a = ptrh[idx], b = ptrh[idx + 1];
        if (b - a == NLON_IN) {
            float v0 = val[a], v1 = val[a + 240], v2 = val[a + 480];
            float d = fmaxf(fabsf(v0 - v1), fmaxf(fabsf(v0 - v2), fabsf(v1 - v2)));
            f = (d < 1e-5f) ? 1 : 0;
        }
    }
    flags[idx] = f;
}

// SoA meta: mx = s0 | (rp*ROWB)<<9  with rp=((h-hbase)%MAXR)*2+par; mc = val*qw.
__global__ void qmeta_kernel(const int* __restrict__ seg, const int* __restrict__ lat,
                             const int* __restrict__ lon, const float* __restrict__ val,
                             const float* __restrict__ qw, const int* __restrict__ hbase,
                             int nnz, unsigned* __restrict__ mx, float* __restrict__ mc) {
    int e = blockIdx.x * blockDim.x + threadIdx.x;
    if (e >= nnz) return;
    int w = lon[e], h = lat[e];
    int i0 = w >> 1;
    int s0 = i0 ? (i0 - 1) : (NLON_OUT - 1);
    int par = w & 1;
    int relh = h - hbase[seg[e]];
    int rp = (relh % MAXR) * 2 + par;            // row-parity slot within window
    mx[e] = (unsigned)s0 | ((unsigned)(rp * ROWB) << 9);
    mc[e] = val[e] * qw[h];
}

// ---------------- main kernel ----------------

__global__ __launch_bounds__(NTHREADS) void disco_kernel(
    const float*    __restrict__ x,
    const unsigned* __restrict__ mx,
    const float*    __restrict__ mc,
    const int*      __restrict__ ptrh,
    const int*      __restrict__ hbase,
    const int*      __restrict__ hlast,
    const int*      __restrict__ flags,
    float*          __restrict__ out)
{
    __shared__ float4 ldsx[MAXR * 2][NLON_OUT];   // 34,560 B -> 4 blocks/CU
    __shared__ float4 rsum_lds[MAXR];
    __shared__ float4 wred[NTHREADS / 64];

    const int tid  = threadIdx.x;
    const int lane = tid & 63, wid = tid >> 6;
    const int bc0  = blockIdx.x * G;
    const int ty   = blockIdx.y;
    const int t    = (ty & 1) ? (NLAT_OUT - 1 - (ty >> 1)) : (ty >> 1);  // poles first
    const int k    = blockIdx.z;
    const int s    = k * NLAT_OUT + t;

    const int hb = hbase[s];
    const int hl = hlast[s];                      // empty seg: hb=1<<28 > hl

    float a0 = 0.f, a1 = 0.f, a2 = 0.f, a3 = 0.f;
    const int p = (tid < NLON_OUT) ? tid : 0;     // pad lanes mirror p=0
    const char* lbase = (const char*)&ldsx[0][0];

#define PROC(mxv, cfv)                                                          \
    {                                                                           \
        const int      s0_  = (int)((mxv) & 511u);                              \
        const unsigned po_  = (mxv) >> 9;                                       \
        int            j2_  = s0_ - p;                                          \
        j2_ += (j2_ >> 31) & NLON_OUT;                                          \
        const float4   xv_  = *(const float4*)(lbase + po_ + ((unsigned)j2_ << 4)); \
        a0 = fmaf((cfv), xv_.x, a0);                                            \
        a1 = fmaf((cfv), xv_.y, a1);                                            \
        a2 = fmaf((cfv), xv_.z, a2);                                            \
        a3 = fmaf((cfv), xv_.w, a3);                                            \
    }

    for (int r0 = hb; r0 <= hl; r0 += MAXR) {
        const int rn = min(MAXR, hl - r0 + 1);
        __syncthreads();                           // prior window readers done
        // ---- stage rows (conflict-free b128 writes) ----
        if (tid < NLON_OUT) {
            for (int r = 0; r < rn; ++r) {
                const float* xr = x + (size_t)bc0 * CHW + (size_t)(r0 + r) * NLON_IN + 2 * tid;
                const float2 v0 = *(const float2*)(xr);
                const float2 v1 = *(const float2*)(xr + CHW);
                const float2 v2 = *(const float2*)(xr + 2 * CHW);
                const float2 v3 = *(const float2*)(xr + 3 * CHW);
                ldsx[2 * r + 0][tid] = make_float4(v0.x, v1.x, v2.x, v3.x);
                ldsx[2 * r + 1][tid] = make_float4(v0.y, v1.y, v2.y, v3.y);
            }
        }
        __syncthreads();
        // ---- rows of this window ----
        for (int r = 0; r < rn; ++r) {
            const int j = (r0 + r) - hb;
            int a = 0, b = 0, fl = 0;
            if (j >= 0 && j < PH - 1) {
                a  = ptrh[s * PH + j];
                b  = ptrh[s * PH + j + 1];
                fl = flags[s * PH + j];
            }
            if (a >= b) continue;                  // uniform
            if (fl) {                              // constant-val full row: cf*rowsum
                float4 v = make_float4(0.f, 0.f, 0.f, 0.f);
                if (tid < NLON_OUT) {
                    const float4 u0 = ldsx[2 * r][tid], u1 = ldsx[2 * r + 1][tid];
                    v = make_float4(u0.x + u1.x, u0.y + u1.y, u0.z + u1.z, u0.w + u1.w);
                }
#pragma unroll
                for (int off = 32; off >= 1; off >>= 1) {
                    v.x += __shfl_down(v.x, off);
                    v.y += __shfl_down(v.y, off);
                    v.z += __shfl_down(v.z, off);
                    v.w += __shfl_down(v.w, off);
                }
                if (lane == 0) wred[wid] = v;
                __syncthreads();
                if (wid == 0) {
                    float4 u = (lane < NTHREADS / 64) ? wred[lane]
                                                      : make_float4(0.f, 0.f, 0.f, 0.f);
#pragma unroll
                    for (int off = 4; off >= 1; off >>= 1) {
                        u.x += __shfl_down(u.x, off);
                        u.y += __shfl_down(u.y, off);
                        u.z += __shfl_down(u.z, off);
                        u.w += __shfl_down(u.w, off);
                    }
                    if (lane == 0) rsum_lds[r] = u;
                }
                __syncthreads();
                const float  cf = mc[a];
                const float4 rs = rsum_lds[r];
                a0 = fmaf(cf, rs.x, a0);
                a1 = fmaf(cf, rs.y, a1);
                a2 = fmaf(cf, rs.z, a2);
                a3 = fmaf(cf, rs.w, a3);
                continue;
            }
            // ---- hot loop over [a,b): peel to 16B alignment, 8 entries/iter ----
            int e = a;
            const int npeel = min(b - a, (4 - (a & 3)) & 3);
            for (int q = 0; q < npeel; ++q, ++e) PROC(mx[e], mc[e]);
            for (; e + 8 <= b; e += 8) {
                const uint4  xA = *(const uint4*)&mx[e];
                const uint4  xB = *(const uint4*)&mx[e + 4];
                const float4 cA = *(const float4*)&mc[e];
                const float4 cB = *(const float4*)&mc[e + 4];
                PROC(xA.x, cA.x); PROC(xA.y, cA.y); PROC(xA.z, cA.z); PROC(xA.w, cA.w);
                PROC(xB.x, cB.x); PROC(xB.y, cB.y); PROC(xB.z, cB.z); PROC(xB.w, cB.w);
            }
            if (e + 4 <= b) {
                const uint4  xA = *(const uint4*)&mx[e];
                const float4 cA = *(const float4*)&mc[e];
                PROC(xA.x, cA.x); PROC(xA.y, cA.y); PROC(xA.z, cA.z); PROC(xA.w, cA.w);
                e += 4;
            }
            for (; e < b; ++e) PROC(mx[e], mc[e]);
        }
    }
#undef PROC

    if (tid < NLON_OUT) {
        const size_t ob = ((size_t)bc0 * NSEG + s) * NLON_OUT + tid;
        out[ob]                            = a0;
        out[ob + (size_t)NSEG * NLON_OUT]     = a1;
        out[ob + (size_t)2 * NSEG * NLON_OUT] = a2;
        out[ob + (size_t)3 * NSEG * NLON_OUT] = a3;
    }
}

// ---------------- fallback (tiny ws): direct kernel ----------------

__global__ __launch_bounds__(384) void disco_simple_kernel(
    const float* __restrict__ x, const float* __restrict__ qw,
    const int* __restrict__ lat, const int* __restrict__ lon,
    const float* __restrict__ val, const int* __restrict__ ptr,
    float* __restrict__ out)
{
    const int p = threadIdx.x;
    if (p >= NLON_OUT) return;
    const int kt = blockIdx.x, bc0 = blockIdx.y * 8;
    const int e0 = ptr[kt], e1 = ptr[kt + 1];
    float acc[8];
#pragma unroll
    for (int g = 0; g < 8; ++g) acc[g] = 0.0f;
    const int pw = 2 * p + 2;
    const float* xb = x + (size_t)bc0 * CHW;
    for (int e = e0; e < e1; ++e) {
        const int h = lat[e], w = lon[e];
        const float cf = val[e] * qw[h];
        int col = w - pw; if (col < 0) col += NLON_IN;
        const float* src = xb + h * NLON_IN + col;
#pragma unroll
        for (int g = 0; g < 8; ++g) acc[g] = fmaf(cf, src[(size_t)g * CHW], acc[g]);
    }
    const size_t ob = ((size_t)bc0 * NSEG + kt) * NLON_OUT + p;
#pragma unroll
    for (int g = 0; g < 8; ++g) out[ob + (size_t)g * NSEG * NLON_OUT] = acc[g];
}

// ---------------- launcher ----------------

extern "C" void kernel_launch(void* const* d_in, const int* in_sizes, int n_in,
                              void* d_out, int out_size, void* d_ws, size_t ws_size,
                              hipStream_t stream)
{
    const float* x   = (const float*)d_in[0];   // [2,64,360,720] f32
    const float* qw  = (const float*)d_in[1];   // [360,1] f32
    const int*   seg = (const int*)  d_in[2];   // [nnz] i32 sorted asc
    const int*   lat = (const int*)  d_in[3];
    const int*   lon = (const int*)  d_in[4];
    const float* val = (const float*)d_in[5];
    const int    nnz = in_sizes[2];

    // ws layout (16B-aligned sections)
    char*  w     = (char*)d_ws;
    int*   ptr   = (int*)w;                         size_t off = 544 * 4;            // 2176
    int*   ptrh  = (int*)(w + off);                 off += (size_t)NSEG * PH * 4;    // +21600
    int*   hbase = (int*)(w + off);                 off += NSEG * 4;                 // +2160
    int*   hlast = (int*)(w + off);                 off += NSEG * 4;                 // +2160
    int*   flags = (int*)(w + off);                 off += (size_t)NSEG * PH * 4;    // +21600 -> 49696 (16B-mult)
    unsigned* mx = (unsigned*)(w + off);            off += (size_t)((nnz + 3) & ~3) * 4;
    float*    mc = (float*)(w + off);               off += (size_t)((nnz + 3) & ~3) * 4;

    segptr_kernel<<<(NSEG + 1 + 255) / 256, 256, 0, stream>>>(seg, nnz, ptr);

    if (ws_size < off) {   // scratch too small: direct (slow but correct) path
        dim3 grid(NSEG, BCTOT / 8);
        disco_simple_kernel<<<grid, 384, 0, stream>>>(x, qw, lat, lon, val, ptr,
                                                      (float*)d_out);
        return;
    }

    ptrh_kernel<<<(NSEG * PH + 255) / 256, 256, 0, stream>>>(lat, ptr, ptrh, hbase, hlast);
    flag_kernel<<<(NSEG * PH + 255) / 256, 256, 0, stream>>>(val, ptrh, flags);
    qmeta_kernel<<<(nnz + 255) / 256, 256, 0, stream>>>(seg, lat, lon, val, qw, hbase,
                                                        nnz, mx, mc);

    dim3 grid(NBCG, NLAT_OUT, KSIZE);
    disco_kernel<<<grid, NTHREADS, 0, stream>>>(x, mx, mc, ptrh, hbase, hlast, flags,
                                                (float*)d_out);
}